// Round 26
// baseline (92.323 us; speedup 1.0000x reference)
//
#include <hip/hip_runtime.h>

// DecorrelationNormalization (group whitening), x: [32,64,64,256] f32 NHWC.
// N = 131072 rows of 256 channels, 16 groups of m=16.
// R26: R25 skeleton (best 89.8us: 512-thr k1, NB=256, TPB=8, double-buffered
// gload_lds, one barrier/tile) with the inner engine switched to
// mfma_f32_32x32x16_bf16 on GROUP-PAIRS: wave wv owns pair gp=wv; per
// 16-row unit ONE set of 8 LDS reads + one cvt8 feeds 32 channels.
// Per wave/tile: 32 b32 reads + ~200 VALU + 12 MFMA (was 128/800/48).
// Fragment + C/D mapping verified end-to-end in R15 (absmax 8.0).
// Partials: [b][gp][33][64] (HH+LL merged, HL, lane-sum) = 17.3MB @ NB=256.

#define NROWS   131072
#define DENOMF  131071.0f
#define EPSV    0.001f

// ws float offsets
#define OFF_INV    0         // [16][256] inv_sqrt row-major
#define OFF_BIAS   4096      // [16][16]
#define OFF_RED    4352      // [16][16896] slice-reduced stats
#define OFF_PART   274688    // [NB][16896] per-block stats
#define GS3        16896     // 8 group-pairs x 33 x 64
#define PWN3       2112      // 33 x 64

typedef __attribute__((ext_vector_type(8)))  short bf16x8;
typedef __attribute__((ext_vector_type(16))) float f32x16;
typedef __attribute__((ext_vector_type(4)))  unsigned int u32x4;

__device__ __forceinline__ unsigned int fbits(float v) {
    return __builtin_bit_cast(unsigned int, v);
}
__device__ __forceinline__ float bfloat(unsigned int u) {
    return __builtin_bit_cast(float, u);
}

// direct HBM->LDS, 16B per lane, wave-uniform LDS base + lane*16
__device__ __forceinline__ void gload_lds16(float* lds, const float* g) {
    __builtin_amdgcn_global_load_lds(
        (const __attribute__((address_space(1))) unsigned int*)g,
        (__attribute__((address_space(3))) unsigned int*)lds, 16, 0, 0);
}

struct Row8 { float a, b, c, d, e, f, g, h; };

// split into hi (truncated bf16) + lo (bf16 of remainder); accumulate f32 sum.
__device__ __forceinline__ void cvt8(const Row8 r, bf16x8& hv, bf16x8& lv, float& s) {
    s += ((r.a + r.b) + (r.c + r.d)) + ((r.e + r.f) + (r.g + r.h));
    const unsigned int ua = fbits(r.a), ub = fbits(r.b), uc = fbits(r.c), ud = fbits(r.d);
    const unsigned int ue = fbits(r.e), uf = fbits(r.f), ug = fbits(r.g), uh = fbits(r.h);
    u32x4 hp;
    hp.x = (ub & 0xFFFF0000u) | (ua >> 16);
    hp.y = (ud & 0xFFFF0000u) | (uc >> 16);
    hp.z = (uf & 0xFFFF0000u) | (ue >> 16);
    hp.w = (uh & 0xFFFF0000u) | (ug >> 16);
    const float da = r.a - bfloat(ua & 0xFFFF0000u);
    const float db = r.b - bfloat(ub & 0xFFFF0000u);
    const float dc = r.c - bfloat(uc & 0xFFFF0000u);
    const float dd = r.d - bfloat(ud & 0xFFFF0000u);
    const float de = r.e - bfloat(ue & 0xFFFF0000u);
    const float df = r.f - bfloat(uf & 0xFFFF0000u);
    const float dg = r.g - bfloat(ug & 0xFFFF0000u);
    const float dh = r.h - bfloat(uh & 0xFFFF0000u);
    u32x4 lp;
    lp.x = (fbits(db) & 0xFFFF0000u) | (fbits(da) >> 16);
    lp.y = (fbits(dd) & 0xFFFF0000u) | (fbits(dc) >> 16);
    lp.z = (fbits(df) & 0xFFFF0000u) | (fbits(de) >> 16);
    lp.w = (fbits(dh) & 0xFFFF0000u) | (fbits(dg) >> 16);
    hv = __builtin_bit_cast(bf16x8, hp);
    lv = __builtin_bit_cast(bf16x8, lp);
}

// ---------------- Phase 1: gload_lds double-buffered 32x32 MFMA Gram ----------------
// grid NB x 512 (8 waves), 1 block/CU (133KB LDS). Block b: TPB=8 tiles of
// 64 rows. STAGE(B,T): wave wv stages rows wv*8+k (one 1KB row per call).
// Wave wv owns group-pair gp=wv (ch = gp*32 + (lane&31), half = lane>>5).
// Per tile 4 units of 16 rows: unit u rows u*16 + half*8 + j (j=0..7);
// k-permutation cancels in X^T X (verified R15). Banks: lanes 0-31
// consecutive, 32-63 offset 8*260 -> 2-way alias, free.
__global__ __launch_bounds__(512, 2) void k1_stats(const float* __restrict__ x,
                                                   float* __restrict__ ws, int NB) {
    __shared__ float xt[2][64 * 260];
    const int tid = threadIdx.x;
    const int lane = tid & 63, wv = tid >> 6;       // wv 0..7 = group pair
    const int TPB = (NROWS / 64) / NB;              // 8 at NB=256
    const size_t tile0 = (size_t)blockIdx.x * TPB;

    const int gp = wv;
    const int hb = (lane >> 5) * 2080 + gp * 32 + (lane & 31);   // half*8*260 + cb

    f32x16 aHH, aHL, aLL;
#pragma unroll
    for (int r = 0; r < 16; ++r) { aHH[r] = 0.f; aHL[r] = 0.f; aLL[r] = 0.f; }
    float s = 0.f;

#define STAGE(B, T)                                                           \
    {                                                                         \
        const float* gpv = x + ((tile0 + (T)) * 64 + (size_t)(wv * 8)) * 256  \
                             + (size_t)lane * 4;                              \
        float* lb = &xt[B][(wv * 8) * 260];                                   \
        gload_lds16(lb + 0 * 260, gpv + 0 * 256);                             \
        gload_lds16(lb + 1 * 260, gpv + 1 * 256);                             \
        gload_lds16(lb + 2 * 260, gpv + 2 * 256);                             \
        gload_lds16(lb + 3 * 260, gpv + 3 * 256);                             \
        gload_lds16(lb + 4 * 260, gpv + 4 * 256);                             \
        gload_lds16(lb + 5 * 260, gpv + 5 * 256);                             \
        gload_lds16(lb + 6 * 260, gpv + 6 * 256);                             \
        gload_lds16(lb + 7 * 260, gpv + 7 * 256);                             \
    }
#define PROCU(BUF, U)                                                         \
    {                                                                         \
        const float* bp = &xt[BUF][(U) * 4160] + hb;                          \
        Row8 r;                                                               \
        r.a = bp[0 * 260]; r.b = bp[1 * 260]; r.c = bp[2 * 260];              \
        r.d = bp[3 * 260]; r.e = bp[4 * 260]; r.f = bp[5 * 260];              \
        r.g = bp[6 * 260]; r.h = bp[7 * 260];                                 \
        bf16x8 hv, lv;                                                        \
        cvt8(r, hv, lv, s);                                                   \
        aHH = __builtin_amdgcn_mfma_f32_32x32x16_bf16(hv, hv, aHH, 0, 0, 0);  \
        aHL = __builtin_amdgcn_mfma_f32_32x32x16_bf16(hv, lv, aHL, 0, 0, 0);  \
        aLL = __builtin_amdgcn_mfma_f32_32x32x16_bf16(lv, lv, aLL, 0, 0, 0);  \
    }
#define PROC4(BUF)                                                            \
    PROCU(BUF, 0); PROCU(BUF, 1); PROCU(BUF, 2); PROCU(BUF, 3);

    STAGE(0, 0);
    for (int t = 0; t < TPB - 1; ++t) {
        __syncthreads();                 // drains tile t's loads; closes buf^1 readers
        STAGE((t + 1) & 1, t + 1);       // direct-to-LDS prefetch of next tile
        PROC4(t & 1);
    }
    __syncthreads();
    PROC4((TPB - 1) & 1);
#undef PROC4
#undef PROCU
#undef STAGE

    // partials: [b][gp][33][64]; vals 0-15 = HH+LL, 16-31 = HL, 32 = lane-sum
    float* pw = ws + OFF_PART + (size_t)blockIdx.x * GS3 + (size_t)gp * PWN3;
#pragma unroll
    for (int r = 0; r < 16; ++r) {
        pw[r * 64 + lane]        = aHH[r] + aLL[r];
        pw[(16 + r) * 64 + lane] = aHL[r];
    }
    pw[32 * 64 + lane] = s;
}

// ---------------- Phase 2a: 2-level block reduction ----------------
// grid (66, 16) x 256. Thread (t, y): red[y][t] = sum over NB/16 blocks.
__global__ __launch_bounds__(256, 4) void k2_reduce(float* __restrict__ ws, int NB) {
    const int t = blockIdx.x * 256 + threadIdx.x;
    if (t >= GS3) return;
    const int per = NB / 16;
    const float* p = ws + OFF_PART + (size_t)(blockIdx.y * per) * GS3 + t;
    float sum = 0.f;
#pragma unroll 8
    for (int b = 0; b < per; ++b) sum += p[(size_t)b * GS3];
    ws[OFF_RED + (size_t)blockIdx.y * GS3 + t] = sum;
}

// ---------------- Phase 2b: gather G -> cov -> cholesky -> inverse ----------------
// 16 blocks x 64 thr. Group g: gp=g>>1, h=g&1. 32x32 C/D mapping (R15-
// verified): entry (T,I,J) at (T*16 + (I&3) + 4*(I>>3))*64 + 32*((I>>2)&1)
// + J; lane-sum at 32*64 + {c, 32+c}.
__global__ void k2_chol(float* __restrict__ ws, int NB) {
    __shared__ float sg[PWN3];
    const int g = blockIdx.x, tid = threadIdx.x;
    const int gp = g >> 1, h = g & 1;

    for (int e = tid; e < PWN3; e += 64) {
        float v = 0.f;
#pragma unroll
        for (int y = 0; y < 16; ++y)
            v += ws[OFF_RED + (size_t)y * GS3 + gp * PWN3 + e];
        sg[e] = v;
    }
    __syncthreads();

    const int ii = tid & 15;
    const float inv_denom = 1.0f / DENOMF;
    const int c32 = 16 * h + ii;
    const float cs_ii = sg[32 * 64 + c32] + sg[32 * 64 + 32 + c32];
    const float mu_l = cs_ii * (1.0f / (float)NROWS);

#define GIDX3(T, I, J) \
    (((T) * 16 + ((I) & 3) + 4 * ((I) >> 3)) * 64 + 32 * (((I) >> 2) & 1) + (J))
    float arow[16];
#pragma unroll
    for (int kk = 0; kk < 16; ++kk) {
        const int I = 16 * h + ii, J = 16 * h + kk;
        float G = sg[GIDX3(0, I, J)] + sg[GIDX3(1, I, J)] + sg[GIDX3(1, J, I)];
        float mu_k = __shfl(mu_l, kk, 64);
        float cv = (G - (float)NROWS * mu_l * mu_k) * inv_denom;    // /(N-1)
        cv = cv * (1.0f - EPSV) + ((kk == ii) ? EPSV : 0.0f);       // shrink
        arow[kk] = cv * inv_denom;                                  // faithful 2nd /(N-1)
    }
#undef GIDX3

    float lrow[16];
#pragma unroll
    for (int j = 0; j < 16; ++j) {
        float diag = __shfl(arow[j], j, 64);
        float ljj  = sqrtf(diag);
        float lij  = (ii == j) ? ljj : arow[j] / ljj;
        lrow[j] = lij;
#pragma unroll
        for (int k = j + 1; k < 16; ++k) {
            float lkj = __shfl(lij, k, 64);
            arow[k] = fmaf(-lij, lkj, arow[k]);
        }
    }

    float xcol[16];
#pragma unroll
    for (int i2 = 0; i2 < 16; ++i2) {
        float ssum = (ii == i2) ? 1.0f : 0.0f;
#pragma unroll
        for (int k = 0; k < 16; ++k) {
            if (k < i2) {
                float Lik = __shfl(lrow[k], i2, 64);
                ssum = fmaf(-Lik, xcol[k], ssum);
            }
        }
        float Lii = __shfl(lrow[i2], i2, 64);
        xcol[i2] = (i2 >= ii) ? ssum / Lii : 0.0f;
    }

    float* invg = ws + OFF_INV + g * 256;
#pragma unroll
    for (int i2 = 0; i2 < 16; ++i2) {
        if (tid < 16) invg[i2 * 16 + tid] = xcol[i2];
        float bi = xcol[i2] * mu_l;
        bi += __shfl_xor(bi, 1, 64);
        bi += __shfl_xor(bi, 2, 64);
        bi += __shfl_xor(bi, 4, 64);
        bi += __shfl_xor(bi, 8, 64);
        if (tid == 0) ws[OFF_BIAS + g * 16 + i2] = bi;
    }
}

// ---------------- Phase 3: apply out = inv*x - bias ----------------
// grid 1024 x 256 thr, branch-free 1-deep prefetch, DPP quad_perm exchange.
template <int CTRL>
__device__ __forceinline__ float dpp1(float v) {
    int iv = __builtin_bit_cast(int, v);
    int r = __builtin_amdgcn_update_dpp(iv, iv, CTRL, 0xF, 0xF, false);
    return __builtin_bit_cast(float, r);
}
template <int CTRL>
__device__ __forceinline__ float4 dpp4(float4 v) {
    float4 r;
    r.x = dpp1<CTRL>(v.x);
    r.y = dpp1<CTRL>(v.y);
    r.z = dpp1<CTRL>(v.z);
    r.w = dpp1<CTRL>(v.w);
    return r;
}

#define DOT4(O, A, V) \
    O = fmaf(A.x, V.x, O); O = fmaf(A.y, V.y, O); \
    O = fmaf(A.z, V.z, O); O = fmaf(A.w, V.w, O)

__global__ __launch_bounds__(256, 4) void k3_apply(const float* __restrict__ x,
                                                   const float* __restrict__ ws,
                                                   float* __restrict__ out) {
    const int tid = threadIdx.x, lane = tid & 63, wv = tid >> 6;
    const int q = lane & 3, g = lane >> 2;

    const float* invg = ws + OFF_INV + g * 256;
#define LOADIR(R, M) \
    *reinterpret_cast<const float4*>(invg + (4 * q + (R)) * 16 + 4 * (q ^ (M)))
    float4 ir00 = LOADIR(0, 0), ir01 = LOADIR(0, 1), ir02 = LOADIR(0, 2), ir03 = LOADIR(0, 3);
    float4 ir10 = LOADIR(1, 0), ir11 = LOADIR(1, 1), ir12 = LOADIR(1, 2), ir13 = LOADIR(1, 3);
    float4 ir20 = LOADIR(2, 0), ir21 = LOADIR(2, 1), ir22 = LOADIR(2, 2), ir23 = LOADIR(2, 3);
    float4 ir30 = LOADIR(3, 0), ir31 = LOADIR(3, 1), ir32 = LOADIR(3, 2), ir33 = LOADIR(3, 3);
#undef LOADIR
    float4 b4 = *reinterpret_cast<const float4*>(ws + OFF_BIAS + g * 16 + 4 * q);

    const int rpb   = NROWS / gridDim.x;   // 128
    const int iters = rpb / 4;             // 32
    const size_t rowbase = (size_t)blockIdx.x * rpb;
    const float4* xp = reinterpret_cast<const float4*>(x) + rowbase * 64 + lane;
    float4*       op = reinterpret_cast<float4*>(out)     + rowbase * 64 + lane;

    float4 cur = xp[(size_t)wv * 64];
    for (int i = 0; i < iters; ++i) {
        const int ip = (i + 1 < iters) ? (i + 1) : (iters - 1);
        float4 nxt = xp[(size_t)(ip * 4 + wv) * 64];

        float4 v0 = cur;
        float4 v1 = dpp4<0xB1>(cur);
        float4 v2 = dpp4<0x4E>(cur);
        float4 v3 = dpp4<0x1B>(cur);

        float o0 = -b4.x, o1 = -b4.y, o2 = -b4.z, o3 = -b4.w;
        DOT4(o0, ir00, v0); DOT4(o0, ir01, v1); DOT4(o0, ir02, v2); DOT4(o0, ir03, v3);
        DOT4(o1, ir10, v0); DOT4(o1, ir11, v1); DOT4(o1, ir12, v2); DOT4(o1, ir13, v3);
        DOT4(o2, ir20, v0); DOT4(o2, ir21, v1); DOT4(o2, ir22, v2); DOT4(o2, ir23, v3);
        DOT4(o3, ir30, v0); DOT4(o3, ir31, v1); DOT4(o3, ir32, v2); DOT4(o3, ir33, v3);

        op[(size_t)(i * 4 + wv) * 64] = make_float4(o0, o1, o2, o3);
        cur = nxt;
    }
}

extern "C" void kernel_launch(void* const* d_in, const int* in_sizes, int n_in,
                              void* d_out, int out_size, void* d_ws, size_t ws_size,
                              hipStream_t stream) {
    const float* x = (const float*)d_in[0];
    float* out = (float*)d_out;
    float* ws  = (float*)d_ws;

    // NB=256 (best shape: 512 thr, TPB=8, 1 block/CU); tier down by ws size.
    int NB = 128;
    if (ws_size >= (size_t)(OFF_PART + 256 * GS3) * sizeof(float)) NB = 256;

    k1_stats<<<NB, 512, 0, stream>>>(x, ws, NB);
    dim3 rg((GS3 + 255) / 256, 16);
    k2_reduce<<<rg, 256, 0, stream>>>(ws, NB);
    k2_chol<<<16, 64, 0, stream>>>(ws, NB);
    k3_apply<<<1024, 256, 0, stream>>>(x, ws, out);
}

// Round 27
// 89.051 us; speedup vs baseline: 1.0367x; 1.0367x over previous
//
#include <hip/hip_runtime.h>

// DecorrelationNormalization (group whitening), x: [32,64,64,256] f32 NHWC.
// N = 131072 rows of 256 channels, 16 groups of m=16.
// R27: R25 (best, 89.8us) + ONE change: k3's out stores are non-temporal.
// out is write-only (never read) -> NT keeps the 128MB out stream from
// evicting x out of the 256MB L3 (x+out = exactly L3; k1 re-fetches 66MB
// from HBM every iteration because of it). R21's NT bundle regressed due
// to NT on partials (written-then-reread -> forced HBM round trip), which
// this round does NOT touch. Everything else byte-identical to R25.

#define NROWS   131072
#define DENOMF  131071.0f
#define EPSV    0.001f

// ws float offsets
#define OFF_INV    0         // [16][256] inv_sqrt row-major
#define OFF_BIAS   4096      // [16][16]
#define OFF_RED    4352      // [16][9216] slice-reduced stats
#define OFF_PART   151808    // [NB][9216] per-block per-group stats
#define GS2        9216      // 16 groups x 9 x 64

typedef __attribute__((ext_vector_type(8))) short bf16x8;
typedef __attribute__((ext_vector_type(4))) float f32x4;
typedef __attribute__((ext_vector_type(4))) unsigned int u32x4;

__device__ __forceinline__ unsigned int fbits(float v) {
    return __builtin_bit_cast(unsigned int, v);
}
__device__ __forceinline__ float bfloat(unsigned int u) {
    return __builtin_bit_cast(float, u);
}

// direct HBM->LDS, 16B per lane, wave-uniform LDS base + lane*16
__device__ __forceinline__ void gload_lds16(float* lds, const float* g) {
    __builtin_amdgcn_global_load_lds(
        (const __attribute__((address_space(1))) unsigned int*)g,
        (__attribute__((address_space(3))) unsigned int*)lds, 16, 0, 0);
}

// non-temporal float4 store (out is write-only; keep it out of L3)
__device__ __forceinline__ void nt_store4(float4 v, float* p) {
    f32x4 t = {v.x, v.y, v.z, v.w};
    __builtin_nontemporal_store(t, reinterpret_cast<f32x4*>(p));
}

struct Row8 { float a, b, c, d, e, f, g, h; };

// split into hi (truncated bf16) + lo (bf16 of remainder); accumulate f32 sum.
__device__ __forceinline__ void cvt8(const Row8 r, bf16x8& hv, bf16x8& lv, float& s) {
    s += ((r.a + r.b) + (r.c + r.d)) + ((r.e + r.f) + (r.g + r.h));
    const unsigned int ua = fbits(r.a), ub = fbits(r.b), uc = fbits(r.c), ud = fbits(r.d);
    const unsigned int ue = fbits(r.e), uf = fbits(r.f), ug = fbits(r.g), uh = fbits(r.h);
    u32x4 hp;
    hp.x = (ub & 0xFFFF0000u) | (ua >> 16);
    hp.y = (ud & 0xFFFF0000u) | (uc >> 16);
    hp.z = (uf & 0xFFFF0000u) | (ue >> 16);
    hp.w = (uh & 0xFFFF0000u) | (ug >> 16);
    const float da = r.a - bfloat(ua & 0xFFFF0000u);
    const float db = r.b - bfloat(ub & 0xFFFF0000u);
    const float dc = r.c - bfloat(uc & 0xFFFF0000u);
    const float dd = r.d - bfloat(ud & 0xFFFF0000u);
    const float de = r.e - bfloat(ue & 0xFFFF0000u);
    const float df = r.f - bfloat(uf & 0xFFFF0000u);
    const float dg = r.g - bfloat(ug & 0xFFFF0000u);
    const float dh = r.h - bfloat(uh & 0xFFFF0000u);
    u32x4 lp;
    lp.x = (fbits(db) & 0xFFFF0000u) | (fbits(da) >> 16);
    lp.y = (fbits(dd) & 0xFFFF0000u) | (fbits(dc) >> 16);
    lp.z = (fbits(df) & 0xFFFF0000u) | (fbits(de) >> 16);
    lp.w = (fbits(dh) & 0xFFFF0000u) | (fbits(dg) >> 16);
    hv = __builtin_bit_cast(bf16x8, hp);
    lv = __builtin_bit_cast(bf16x8, lp);
}

// ---------------- Phase 1: gload_lds double-buffered MFMA Gram ----------------
// grid NB x 512 (8 waves), 1 block/CU (133KB LDS). Block b: TPB=8 tiles of
// 64 rows. STAGE(B,T): wave wv stages rows wv*8+k (k=0..7) of the tile,
// one 1KB row per global_load_lds call. One barrier per tile; loads for
// t+1 in flight across all of tile t's MFMA. Wave wv: groups 2wv, 2wv+1;
// 2 units (rows 0-31, 32-63); lane ch = g*16+(lane&15), slot = lane>>4;
// unit rows u*32 + slot*8 + ((j+2*slot)&7) (stagger -> 2-way banks, benign).
__global__ __launch_bounds__(512, 2) void k1_stats(const float* __restrict__ x,
                                                   float* __restrict__ ws, int NB) {
    __shared__ float xt[2][64 * 260];
    const int tid = threadIdx.x;
    const int lane = tid & 63, wv = tid >> 6;       // wv 0..7
    const int slot = lane >> 4;
    const int TPB = (NROWS / 64) / NB;              // 8 at NB=256
    const size_t tile0 = (size_t)blockIdx.x * TPB;

    const int g0 = wv * 2;
    const int rb0 = g0 * 16 + (lane & 15);
    const int roA0 = (slot * 8 + ((0 + 2 * slot) & 7)) * 260 + rb0;
    const int roA1 = (slot * 8 + ((1 + 2 * slot) & 7)) * 260 + rb0;
    const int roA2 = (slot * 8 + ((2 + 2 * slot) & 7)) * 260 + rb0;
    const int roA3 = (slot * 8 + ((3 + 2 * slot) & 7)) * 260 + rb0;
    const int roA4 = (slot * 8 + ((4 + 2 * slot) & 7)) * 260 + rb0;
    const int roA5 = (slot * 8 + ((5 + 2 * slot) & 7)) * 260 + rb0;
    const int roA6 = (slot * 8 + ((6 + 2 * slot) & 7)) * 260 + rb0;
    const int roA7 = (slot * 8 + ((7 + 2 * slot) & 7)) * 260 + rb0;
    const int roB0 = roA0 + 32 * 260, roB1 = roA1 + 32 * 260;
    const int roB2 = roA2 + 32 * 260, roB3 = roA3 + 32 * 260;
    const int roB4 = roA4 + 32 * 260, roB5 = roA5 + 32 * 260;
    const int roB6 = roA6 + 32 * 260, roB7 = roA7 + 32 * 260;

    f32x4 hh0 = {0,0,0,0}, hl0 = {0,0,0,0}, ll0 = {0,0,0,0};
    f32x4 hh1 = {0,0,0,0}, hl1 = {0,0,0,0}, ll1 = {0,0,0,0};
    float s0 = 0.f, s1 = 0.f;

#define STAGE(B, T)                                                           \
    {                                                                         \
        const float* gp = x + ((tile0 + (T)) * 64 + (size_t)(wv * 8)) * 256   \
                            + (size_t)lane * 4;                               \
        float* lb = &xt[B][(wv * 8) * 260];                                   \
        gload_lds16(lb + 0 * 260, gp + 0 * 256);                              \
        gload_lds16(lb + 1 * 260, gp + 1 * 256);                              \
        gload_lds16(lb + 2 * 260, gp + 2 * 256);                              \
        gload_lds16(lb + 3 * 260, gp + 3 * 256);                              \
        gload_lds16(lb + 4 * 260, gp + 4 * 256);                              \
        gload_lds16(lb + 5 * 260, gp + 5 * 256);                              \
        gload_lds16(lb + 6 * 260, gp + 6 * 256);                              \
        gload_lds16(lb + 7 * 260, gp + 7 * 256);                              \
    }
#define PROCG(BUF, U, G, AHH, AHL, ALL, S)                                    \
    {                                                                         \
        const float* bp = &xt[BUF][0];                                        \
        Row8 r;                                                               \
        r.a = bp[ro##U##0 + (G) * 16]; r.b = bp[ro##U##1 + (G) * 16];         \
        r.c = bp[ro##U##2 + (G) * 16]; r.d = bp[ro##U##3 + (G) * 16];         \
        r.e = bp[ro##U##4 + (G) * 16]; r.f = bp[ro##U##5 + (G) * 16];         \
        r.g = bp[ro##U##6 + (G) * 16]; r.h = bp[ro##U##7 + (G) * 16];         \
        bf16x8 hv, lv;                                                        \
        cvt8(r, hv, lv, S);                                                   \
        AHH = __builtin_amdgcn_mfma_f32_16x16x32_bf16(hv, hv, AHH, 0, 0, 0);  \
        AHL = __builtin_amdgcn_mfma_f32_16x16x32_bf16(hv, lv, AHL, 0, 0, 0);  \
        ALL = __builtin_amdgcn_mfma_f32_16x16x32_bf16(lv, lv, ALL, 0, 0, 0);  \
    }
#define PROC4(BUF)                                                            \
    PROCG(BUF, A, 0, hh0, hl0, ll0, s0);                                      \
    PROCG(BUF, B, 0, hh0, hl0, ll0, s0);                                      \
    PROCG(BUF, A, 1, hh1, hl1, ll1, s1);                                      \
    PROCG(BUF, B, 1, hh1, hl1, ll1, s1);

    STAGE(0, 0);
    for (int t = 0; t < TPB - 1; ++t) {
        __syncthreads();                 // drains tile t's loads; closes buf^1 readers
        STAGE((t + 1) & 1, t + 1);       // direct-to-LDS prefetch of next tile
        PROC4(t & 1);
    }
    __syncthreads();
    PROC4((TPB - 1) & 1);
#undef PROC4
#undef PROCG
#undef STAGE

    // partials: [b][g][9][64], g = 2wv+G; regs 0-3 = HH+LL, 4-7 = HL, 8 = sum
    float* pb = ws + OFF_PART + (size_t)blockIdx.x * GS2 + (size_t)g0 * 576;
#define STG(G, AHH, AHL, ALL, S)                                              \
    {                                                                         \
        float* pw = pb + (G) * 576;                                           \
        pw[0 * 64 + lane] = AHH[0] + ALL[0];                                  \
        pw[1 * 64 + lane] = AHH[1] + ALL[1];                                  \
        pw[2 * 64 + lane] = AHH[2] + ALL[2];                                  \
        pw[3 * 64 + lane] = AHH[3] + ALL[3];                                  \
        pw[4 * 64 + lane] = AHL[0]; pw[5 * 64 + lane] = AHL[1];               \
        pw[6 * 64 + lane] = AHL[2]; pw[7 * 64 + lane] = AHL[3];               \
        pw[8 * 64 + lane] = S;                                                \
    }
    STG(0, hh0, hl0, ll0, s0);
    STG(1, hh1, hl1, ll1, s1);
#undef STG
}

// ---------------- Phase 2a: 2-level block reduction ----------------
// grid (36, 16) x 256. Thread (t, y): red[y][t] = sum over NB/16 blocks.
__global__ __launch_bounds__(256, 4) void k2_reduce(float* __restrict__ ws, int NB) {
    const int t = blockIdx.x * 256 + threadIdx.x;
    if (t >= GS2) return;
    const int per = NB / 16;
    const float* p = ws + OFF_PART + (size_t)(blockIdx.y * per) * GS2 + t;
    float sum = 0.f;
#pragma unroll 8
    for (int b = 0; b < per; ++b) sum += p[(size_t)b * GS2];
    ws[OFF_RED + (size_t)blockIdx.y * GS2 + t] = sum;
}

// ---------------- Phase 2b: gather G -> cov -> cholesky -> inverse ----------------
// sg layout: HHLL regs 0-3 (0..255), HL regs 4-7 (256..511), sums (512..575);
// T[i][j] at T*256 + (i&3)*64 + ((i>>2)<<4) + j. Validated R22/R23 (absmax 8.0).
__device__ __forceinline__ void chol_from_sg(const float* sg, int g, int tid,
                                             float* __restrict__ ws) {
    const int ii = tid & 15;
    const float inv_denom = 1.0f / DENOMF;
    const float cs_ii = sg[512 + ii] + sg[512 + 16 + ii] +
                        sg[512 + 32 + ii] + sg[512 + 48 + ii];
    const float mu_l = cs_ii * (1.0f / (float)NROWS);

#define GIDX2(T, I, J) ((T) * 256 + ((I) & 3) * 64 + ((((I) >> 2)) << 4) + (J))
    float arow[16];
#pragma unroll
    for (int kk = 0; kk < 16; ++kk) {
        float G = sg[GIDX2(0, ii, kk)] + sg[GIDX2(1, ii, kk)] + sg[GIDX2(1, kk, ii)];
        float mu_k = __shfl(mu_l, kk, 64);
        float cv = (G - (float)NROWS * mu_l * mu_k) * inv_denom;    // /(N-1)
        cv = cv * (1.0f - EPSV) + ((kk == ii) ? EPSV : 0.0f);       // shrink
        arow[kk] = cv * inv_denom;                                  // faithful 2nd /(N-1)
    }
#undef GIDX2

    float lrow[16];
#pragma unroll
    for (int j = 0; j < 16; ++j) {
        float diag = __shfl(arow[j], j, 64);
        float ljj  = sqrtf(diag);
        float lij  = (ii == j) ? ljj : arow[j] / ljj;
        lrow[j] = lij;
#pragma unroll
        for (int k = j + 1; k < 16; ++k) {
            float lkj = __shfl(lij, k, 64);
            arow[k] = fmaf(-lij, lkj, arow[k]);
        }
    }

    float xcol[16];
#pragma unroll
    for (int i2 = 0; i2 < 16; ++i2) {
        float ssum = (ii == i2) ? 1.0f : 0.0f;
#pragma unroll
        for (int k = 0; k < 16; ++k) {
            if (k < i2) {
                float Lik = __shfl(lrow[k], i2, 64);
                ssum = fmaf(-Lik, xcol[k], ssum);
            }
        }
        float Lii = __shfl(lrow[i2], i2, 64);
        xcol[i2] = (i2 >= ii) ? ssum / Lii : 0.0f;
    }

    float* invg = ws + OFF_INV + g * 256;
#pragma unroll
    for (int i2 = 0; i2 < 16; ++i2) {
        if (tid < 16) invg[i2 * 16 + tid] = xcol[i2];
        float bi = xcol[i2] * mu_l;
        bi += __shfl_xor(bi, 1, 64);
        bi += __shfl_xor(bi, 2, 64);
        bi += __shfl_xor(bi, 4, 64);
        bi += __shfl_xor(bi, 8, 64);
        if (tid == 0) ws[OFF_BIAS + g * 16 + i2] = bi;
    }
}

__global__ void k2_chol(float* __restrict__ ws, int NB) {
    __shared__ float sg[576];
    const int g = blockIdx.x, tid = threadIdx.x;

    for (int e = tid; e < 576; e += 64) {
        float v = 0.f;
#pragma unroll
        for (int y = 0; y < 16; ++y)
            v += ws[OFF_RED + (size_t)y * GS2 + g * 576 + e];
        sg[e] = v;
    }
    __syncthreads();
    chol_from_sg(sg, g, tid, ws);
}

// ---------------- Phase 3: apply out = inv*x - bias (NT out stores) ----------------
// grid 1024 x 256 thr, branch-free 1-deep prefetch, DPP quad_perm exchange.
template <int CTRL>
__device__ __forceinline__ float dpp1(float v) {
    int iv = __builtin_bit_cast(int, v);
    int r = __builtin_amdgcn_update_dpp(iv, iv, CTRL, 0xF, 0xF, false);
    return __builtin_bit_cast(float, r);
}
template <int CTRL>
__device__ __forceinline__ float4 dpp4(float4 v) {
    float4 r;
    r.x = dpp1<CTRL>(v.x);
    r.y = dpp1<CTRL>(v.y);
    r.z = dpp1<CTRL>(v.z);
    r.w = dpp1<CTRL>(v.w);
    return r;
}

#define DOT4(O, A, V) \
    O = fmaf(A.x, V.x, O); O = fmaf(A.y, V.y, O); \
    O = fmaf(A.z, V.z, O); O = fmaf(A.w, V.w, O)

__global__ __launch_bounds__(256, 4) void k3_apply(const float* __restrict__ x,
                                                   const float* __restrict__ ws,
                                                   float* __restrict__ out) {
    const int tid = threadIdx.x, lane = tid & 63, wv = tid >> 6;
    const int q = lane & 3, g = lane >> 2;

    const float* invg = ws + OFF_INV + g * 256;
#define LOADIR(R, M) \
    *reinterpret_cast<const float4*>(invg + (4 * q + (R)) * 16 + 4 * (q ^ (M)))
    float4 ir00 = LOADIR(0, 0), ir01 = LOADIR(0, 1), ir02 = LOADIR(0, 2), ir03 = LOADIR(0, 3);
    float4 ir10 = LOADIR(1, 0), ir11 = LOADIR(1, 1), ir12 = LOADIR(1, 2), ir13 = LOADIR(1, 3);
    float4 ir20 = LOADIR(2, 0), ir21 = LOADIR(2, 1), ir22 = LOADIR(2, 2), ir23 = LOADIR(2, 3);
    float4 ir30 = LOADIR(3, 0), ir31 = LOADIR(3, 1), ir32 = LOADIR(3, 2), ir33 = LOADIR(3, 3);
#undef LOADIR
    float4 b4 = *reinterpret_cast<const float4*>(ws + OFF_BIAS + g * 16 + 4 * q);

    const int rpb   = NROWS / gridDim.x;   // 128
    const int iters = rpb / 4;             // 32
    const size_t rowbase = (size_t)blockIdx.x * rpb;
    const float4* xp = reinterpret_cast<const float4*>(x) + rowbase * 64 + lane;
    float*        ob = out + (rowbase * 64 + lane) * 4;

    float4 cur = xp[(size_t)wv * 64];
    for (int i = 0; i < iters; ++i) {
        const int ip = (i + 1 < iters) ? (i + 1) : (iters - 1);
        float4 nxt = xp[(size_t)(ip * 4 + wv) * 64];

        float4 v0 = cur;
        float4 v1 = dpp4<0xB1>(cur);
        float4 v2 = dpp4<0x4E>(cur);
        float4 v3 = dpp4<0x1B>(cur);

        float o0 = -b4.x, o1 = -b4.y, o2 = -b4.z, o3 = -b4.w;
        DOT4(o0, ir00, v0); DOT4(o0, ir01, v1); DOT4(o0, ir02, v2); DOT4(o0, ir03, v3);
        DOT4(o1, ir10, v0); DOT4(o1, ir11, v1); DOT4(o1, ir12, v2); DOT4(o1, ir13, v3);
        DOT4(o2, ir20, v0); DOT4(o2, ir21, v1); DOT4(o2, ir22, v2); DOT4(o2, ir23, v3);
        DOT4(o3, ir30, v0); DOT4(o3, ir31, v1); DOT4(o3, ir32, v2); DOT4(o3, ir33, v3);

        nt_store4(make_float4(o0, o1, o2, o3), ob + (size_t)(i * 4 + wv) * 256);
        cur = nxt;
    }
}

extern "C" void kernel_launch(void* const* d_in, const int* in_sizes, int n_in,
                              void* d_out, int out_size, void* d_ws, size_t ws_size,
                              hipStream_t stream) {
    const float* x = (const float*)d_in[0];
    float* out = (float*)d_out;
    float* ws  = (float*)d_ws;

    // NB=256 (R25 best shape: 512 thr, TPB=8, 1 block/CU); tier down by ws.
    int NB = 128;
    if (ws_size >= (size_t)(OFF_PART + 256 * GS2) * sizeof(float)) NB = 256;

    k1_stats<<<NB, 512, 0, stream>>>(x, ws, NB);
    dim3 rg((GS2 + 255) / 256, 16);
    k2_reduce<<<rg, 256, 0, stream>>>(ws, NB);
    k2_chol<<<16, 64, 0, stream>>>(ws, NB);
    k3_apply<<<1024, 256, 0, stream>>>(x, ws, out);
}